// Round 16
// baseline (191.744 us; speedup 1.0000x reference)
//
#include <hip/hip_runtime.h>
#include <hip/hip_bf16.h>

typedef __attribute__((ext_vector_type(2))) _Float16 f16x2;
typedef __attribute__((ext_vector_type(4))) _Float16 f16x4;
typedef __attribute__((ext_vector_type(8))) _Float16 f16x8;
typedef __attribute__((ext_vector_type(4))) float f32x4;

#define B_ 8
#define N_ 4096
#define C_ 64
#define CQ_ 32
#define SPLIT 4
#define KEYS (N_ / SPLIT)
#define NT (KEYS / 64)   // 16
#define QB 128           // queries per block (4 waves x 32)

#define L2E_ 1.4426950408889634f
#define LOG2L_ 0.5287663729448977f

// minimax cubic for 2^y on [0, 1.443]
#define P0_ 0.9992f
#define P1_ 0.70591f
#define P2_ 0.20093f
#define P3_ 0.094395f

__device__ __forceinline__ void async16(void* lds, const void* gsrc) {
    __builtin_amdgcn_global_load_lds(
        (const __attribute__((address_space(1))) unsigned int*)gsrc,
        (__attribute__((address_space(3))) unsigned int*)lds, 16, 0, 0);
}

// packed f16 evaluation of 2^z on z in [0, 1.443]
__device__ __forceinline__ f16x2 wpoly(float z0, float z1) {
    f16x2 h = __builtin_bit_cast(f16x2, __builtin_amdgcn_cvt_pkrtz(z0, z1));
    const _Float16 c3 = (_Float16)P3_, c2 = (_Float16)P2_;
    const _Float16 c1 = (_Float16)P1_, c0 = (_Float16)P0_;
    return ((h * c3 + c2) * h + c1) * h + c0;
}

// ---------------- projection kernel v8: MFMA-based 1x1 conv (r15, + cnt zeroing) ----------------
__global__ __launch_bounds__(256) void proj_kernel(
    const float* __restrict__ x,
    const float* __restrict__ Wq, const float* __restrict__ bq,
    const float* __restrict__ Wk, const float* __restrict__ bk,
    const float* __restrict__ Wv, const float* __restrict__ bv,
    const float* __restrict__ sigp,
    _Float16* __restrict__ qh, _Float16* __restrict__ khf,
    _Float16* __restrict__ vhf,
    float* __restrict__ nqs, float* __restrict__ nkf,
    int* __restrict__ cnt)
{
    __shared__ __align__(16) _Float16 xs16[64][72];   // [pix][ch] f16
    __shared__ __align__(16) _Float16 vtmp[64][76];   // [ch][pix] f16

    const int t = threadIdx.x;
    const int wid = __builtin_amdgcn_readfirstlane(t >> 6);
    const int l = t & 63;
    const int lg = l >> 4;
    const int lm = l & 15;
    const int b = blockIdx.x >> 6;
    const int tile = blockIdx.x & 63;
    const int n0 = tile * 64;
    const size_t bN = (size_t)b * N_;

    if (blockIdx.x == 0) cnt[t] = 0;   // reset family counters every launch

    // ---- stage x tile transposed to f16 ----
    {
        const int c = t >> 2, pq = t & 3;
        const float* xp = x + ((size_t)b * C_ + c) * N_ + n0 + pq * 16;
        f32x4 a0 = *(const f32x4*)(xp);
        f32x4 a1 = *(const f32x4*)(xp + 4);
        f32x4 a2 = *(const f32x4*)(xp + 8);
        f32x4 a3 = *(const f32x4*)(xp + 12);
        #pragma unroll
        for (int i = 0; i < 4; ++i) {
            xs16[pq * 16 + i][c]      = (_Float16)a0[i];
            xs16[pq * 16 + 4 + i][c]  = (_Float16)a1[i];
            xs16[pq * 16 + 8 + i][c]  = (_Float16)a2[i];
            xs16[pq * 16 + 12 + i][c] = (_Float16)a3[i];
        }
    }
    __syncthreads();

    const float* Wr;
    const float* br;
    if (wid == 0)      { Wr = Wq;            br = bq; }
    else if (wid == 1) { Wr = Wk;            br = bk; }
    else if (wid == 2) { Wr = Wv;            br = bv; }
    else               { Wr = Wv + 32 * 64;  br = bv + 32; }

    f16x8 af[2][2];
    #pragma unroll
    for (int og = 0; og < 2; ++og) {
        #pragma unroll
        for (int ks = 0; ks < 2; ++ks) {
            const float* wp = Wr + (og * 16 + lm) * 64 + ks * 32 + lg * 8;
            const f32x4 w0 = *(const f32x4*)(wp);
            const f32x4 w1 = *(const f32x4*)(wp + 4);
            f16x8 h;
            #pragma unroll
            for (int e = 0; e < 4; ++e) { h[e] = (_Float16)w0[e]; h[4 + e] = (_Float16)w1[e]; }
            af[og][ks] = h;
        }
    }
    f32x4 bias[2];
    #pragma unroll
    for (int og = 0; og < 2; ++og)
        bias[og] = *(const f32x4*)(br + og * 16 + lg * 4);

    f32x4 d[2][4];
    #pragma unroll
    for (int pg = 0; pg < 4; ++pg) {
        const f16x8 bf0 = *(const f16x8*)(&xs16[pg * 16 + lm][lg * 8]);
        const f16x8 bf1 = *(const f16x8*)(&xs16[pg * 16 + lm][32 + lg * 8]);
        #pragma unroll
        for (int og = 0; og < 2; ++og) {
            f32x4 acc = __builtin_amdgcn_mfma_f32_16x16x32_f16(af[og][0], bf0, bias[og], 0, 0, 0);
            d[og][pg] = __builtin_amdgcn_mfma_f32_16x16x32_f16(af[og][1], bf1, acc, 0, 0, 0);
        }
    }

    const float sv = sigp[0];
    const float cdL = 0.7213475204444817f / (sv * sv);
    const float c1 = 2.0f * cdL;

    if (wid < 2) {
        float s[4];
        #pragma unroll
        for (int pg = 0; pg < 4; ++pg) {
            float acc = 0.f;
            #pragma unroll
            for (int og = 0; og < 2; ++og)
                #pragma unroll
                for (int r = 0; r < 4; ++r)
                    acc = fmaf(d[og][pg][r], d[og][pg][r], acc);
            acc += __shfl_xor(acc, 16);
            acc += __shfl_xor(acc, 32);
            s[pg] = acc;
        }
        if (wid == 0) {
            #pragma unroll
            for (int og = 0; og < 2; ++og) {
                #pragma unroll
                for (int pg = 0; pg < 4; ++pg) {
                    f16x4 h;
                    #pragma unroll
                    for (int r = 0; r < 4; ++r) h[r] = (_Float16)(d[og][pg][r] * c1);
                    *(f16x4*)(qh + (bN + n0 + pg * 16 + lm) * CQ_ + og * 16 + lg * 4) = h;
                }
            }
            if (l < 16) {
                #pragma unroll
                for (int pg = 0; pg < 4; ++pg)
                    nqs[bN + n0 + pg * 16 + l] = LOG2L_ - s[pg] * cdL;
            }
        } else {
            const size_t tbase = ((size_t)b * (N_ / 64) + tile) * 4;
            #pragma unroll
            for (int og = 0; og < 2; ++og) {
                const int g = og * 2 + (lg >> 1);
                const int e0 = (lg & 1) * 4;
                #pragma unroll
                for (int pg = 0; pg < 4; ++pg) {
                    f16x4 h;
                    #pragma unroll
                    for (int r = 0; r < 4; ++r) h[r] = (_Float16)d[og][pg][r];
                    *(f16x4*)(khf + (tbase + g) * 512 + (pg * 16 + lm) * 8 + e0) = h;
                }
            }
            if (l < 16) {
                #pragma unroll
                for (int pg = 0; pg < 4; ++pg) {
                    const int kkg = n0 + pg * 16 + l;
                    const int kk = kkg & 31;
                    const int kap = (((kk & 15) >> 2) << 3) + (kk & 3) + (((kk >> 4) & 1) << 2);
                    nkf[((size_t)b * (N_ / 32) + (kkg >> 5)) * 32 + kap] = -s[pg] * cdL;
                }
            }
        }
    } else {
        const int co = (wid - 2) * 32;
        #pragma unroll
        for (int og = 0; og < 2; ++og)
            #pragma unroll
            for (int pg = 0; pg < 4; ++pg)
                #pragma unroll
                for (int r = 0; r < 4; ++r)
                    vtmp[co + og * 16 + lg * 4 + r][pg * 16 + lm] = (_Float16)d[og][pg][r];
    }
    __syncthreads();

    #pragma unroll
    for (int p = 0; p < 2; ++p) {
        const int jg = (t >> 6) + p * 4;
        const int ch = t & 63;
        const int p0 = (jg >> 2) * 32 + (jg & 3) * 4;
        const f16x4 a0 = *(const f16x4*)(&vtmp[ch][p0]);
        const f16x4 a1 = *(const f16x4*)(&vtmp[ch][p0 + 16]);
        f16x8 hv;
        #pragma unroll
        for (int e = 0; e < 4; ++e) { hv[e] = a0[e]; hv[4 + e] = a1[e]; }
        *(f16x8*)(vhf + ((size_t)b * (N_ / 64) + tile) * 4096 + (size_t)(jg * 64 + ch) * 8) = hv;
    }
}

// ---------------- fused RBF-attention v16: r11 core + last-block combine ----------------
// grid 1024, 256 threads (4 waves), 4 blocks/CU, 32 q/wave. Rolled loop, tri-buffer.
// The 4 split-partners of a (b,qblk) family are consecutive wgid -> same XCD/L2.
// Last-arriving partner (atomic counter) combines partials and writes out.
__global__ __launch_bounds__(256, 4) void attn_kernel(
    const float* __restrict__ x,
    const _Float16* __restrict__ qh,
    const _Float16* __restrict__ khf,
    const _Float16* __restrict__ vhf,
    const float* __restrict__ nqs,
    const float* __restrict__ nkf,
    _Float16* __restrict__ opart,
    float* __restrict__ dpart,
    int* __restrict__ cnt,
    float* __restrict__ out)
{
    __shared__ __align__(16) _Float16 Kb[3][2048];   // per tile: [g:4][key:64][8]
    __shared__ __align__(16) _Float16 Vb[3][4096];   // per tile: [j:2][g:4][ch:64][8]
    __shared__ __align__(16) float sNkAll[1024];     // nk for all KEYS (kappa order)
    __shared__ int sdone;

    const int t = threadIdx.x;
    const int wid = t >> 6;
    const int l = t & 63;
    const int lg = l >> 4;
    const int lm = l & 15;

    // bijective XCD swizzle (grid 1024): 128 consecutive wgid per XCD
    const int orig = blockIdx.x;
    const int wgid = (orig & 7) * 128 + (orig >> 3);
    const int qblk = wgid & 31;
    const int fam = wgid >> 5;                 // b*SPLIT + split
    const int split = fam & (SPLIT - 1);
    const int b = fam >> 2;
    const int qbase = qblk * QB + wid * 32;
    const int k0 = split * KEYS;
    const size_t bN = (size_t)b * N_;

    const f16x8 qfA = *(const f16x8*)(qh + (bN + qbase + lm) * CQ_ + 8 * lg);
    const f16x8 qfB = *(const f16x8*)(qh + (bN + qbase + 16 + lm) * CQ_ + 8 * lg);
    const float nqA = nqs[bN + qbase + lm];
    const float nqB = nqs[bN + qbase + 16 + lm];

    const _Float16* kg = khf + ((size_t)b * (N_ / 64) + (k0 >> 6)) * 2048 + wid * 512 + l * 8;
    const _Float16* vg = vhf + ((size_t)b * (N_ / 64) + (k0 >> 6)) * 4096 + wid * 1024 + l * 8;
    const float* nkp = nkf + bN + k0 + wid * 256 + l * 4;

    f32x4 accA[4], accB[4], accdA, accdB;
    #pragma unroll
    for (int i = 0; i < 4; ++i) {
        accA[i] = (f32x4){0.f, 0.f, 0.f, 0.f};
        accB[i] = (f32x4){0.f, 0.f, 0.f, 0.f};
    }
    accdA = (f32x4){0.f, 0.f, 0.f, 0.f};
    accdB = (f32x4){0.f, 0.f, 0.f, 0.f};
    f16x8 ones;
    #pragma unroll
    for (int e = 0; e < 8; ++e) ones[e] = (_Float16)1.0f;

    f16x8 paJ0A, paJ0B, paJ1A, paJ1B;

    auto ISSUE = [&](int tile, int bf) {
        async16(&Kb[bf][wid * 512],        kg + (size_t)tile * 2048);
        async16(&Vb[bf][wid * 1024],       vg + (size_t)tile * 4096);
        async16(&Vb[bf][wid * 1024 + 512], vg + (size_t)tile * 4096 + 512);
    };

    auto HALF = [&](int J, int tt, int ck, int cv, bool doPV, f16x8& pA, f16x8& pB) {
        const f16x8 kf0 = *(const f16x8*)(&Kb[ck][(lg * 64 + J * 32 + lm) * 8]);
        const f16x8 kf1 = *(const f16x8*)(&Kb[ck][(lg * 64 + J * 32 + 16 + lm) * 8]);
        const f32x4 NK0 = *(const f32x4*)(&sNkAll[tt * 64 + J * 32 + lg * 8]);
        const f32x4 NK1 = *(const f32x4*)(&sNkAll[tt * 64 + J * 32 + lg * 8 + 4]);
        f32x4 CA0, CA1, CB0, CB1;
        #pragma unroll
        for (int r = 0; r < 4; ++r) {
            CA0[r] = NK0[r] + nqA; CA1[r] = NK1[r] + nqA;
            CB0[r] = NK0[r] + nqB; CB1[r] = NK1[r] + nqB;
        }
        __builtin_amdgcn_s_setprio(1);
        const f32x4 SA0 = __builtin_amdgcn_mfma_f32_16x16x32_f16(kf0, qfA, CA0, 0, 0, 0);
        const f32x4 SA1 = __builtin_amdgcn_mfma_f32_16x16x32_f16(kf1, qfA, CA1, 0, 0, 0);
        const f32x4 SB0 = __builtin_amdgcn_mfma_f32_16x16x32_f16(kf0, qfB, CB0, 0, 0, 0);
        const f32x4 SB1 = __builtin_amdgcn_mfma_f32_16x16x32_f16(kf1, qfB, CB1, 0, 0, 0);
        __builtin_amdgcn_s_setprio(0);
        if (doPV) {
            __builtin_amdgcn_s_setprio(1);
            #pragma unroll
            for (int tc = 0; tc < 4; ++tc) {
                const f16x8 vf = *(const f16x8*)(&Vb[cv][((J * 4 + lg) * 64 + tc * 16 + lm) * 8]);
                accA[tc] = __builtin_amdgcn_mfma_f32_16x16x32_f16(pA, vf, accA[tc], 0, 0, 0);
                accB[tc] = __builtin_amdgcn_mfma_f32_16x16x32_f16(pB, vf, accB[tc], 0, 0, 0);
            }
            accdA = __builtin_amdgcn_mfma_f32_16x16x32_f16(pA, ones, accdA, 0, 0, 0);
            accdB = __builtin_amdgcn_mfma_f32_16x16x32_f16(pB, ones, accdB, 0, 0, 0);
            __builtin_amdgcn_s_setprio(0);
        }
        f16x2 w;
        w = wpoly(__builtin_amdgcn_exp2f(SA0[0]), __builtin_amdgcn_exp2f(SA0[1])); pA[0] = w[0]; pA[1] = w[1];
        w = wpoly(__builtin_amdgcn_exp2f(SA0[2]), __builtin_amdgcn_exp2f(SA0[3])); pA[2] = w[0]; pA[3] = w[1];
        w = wpoly(__builtin_amdgcn_exp2f(SA1[0]), __builtin_amdgcn_exp2f(SA1[1])); pA[4] = w[0]; pA[5] = w[1];
        w = wpoly(__builtin_amdgcn_exp2f(SA1[2]), __builtin_amdgcn_exp2f(SA1[3])); pA[6] = w[0]; pA[7] = w[1];
        w = wpoly(__builtin_amdgcn_exp2f(SB0[0]), __builtin_amdgcn_exp2f(SB0[1])); pB[0] = w[0]; pB[1] = w[1];
        w = wpoly(__builtin_amdgcn_exp2f(SB0[2]), __builtin_amdgcn_exp2f(SB0[3])); pB[2] = w[0]; pB[3] = w[1];
        w = wpoly(__builtin_amdgcn_exp2f(SB1[0]), __builtin_amdgcn_exp2f(SB1[1])); pB[4] = w[0]; pB[5] = w[1];
        w = wpoly(__builtin_amdgcn_exp2f(SB1[2]), __builtin_amdgcn_exp2f(SB1[3])); pB[6] = w[0]; pB[7] = w[1];
    };

    // ---- prologue ----
    async16(&sNkAll[wid * 256], nkp);
    ISSUE(0, 0);
    asm volatile("s_waitcnt vmcnt(0)" ::: "memory");
    asm volatile("s_barrier" ::: "memory");
    ISSUE(1, 1);
    HALF(0, 0, 0, 0, false, paJ0A, paJ0B);
    HALF(1, 0, 0, 0, false, paJ1A, paJ1B);

    int cv = 0, ck = 1, ib = 2;
    #pragma unroll 1
    for (int tt = 1; tt < NT; ++tt) {
        asm volatile("s_waitcnt vmcnt(0)" ::: "memory");
        asm volatile("s_barrier" ::: "memory");
        if (tt + 1 < NT) ISSUE(tt + 1, ib);
        HALF(0, tt, ck, cv, true, paJ0A, paJ0B);
        HALF(1, tt, ck, cv, true, paJ1A, paJ1B);
        const int tmp = cv; cv = ck; ck = ib; ib = tmp;
    }

    // ---- epilogue PV ----
    __builtin_amdgcn_s_setprio(1);
    #pragma unroll
    for (int J = 0; J < 2; ++J) {
        const f16x8& pA = J ? paJ1A : paJ0A;
        const f16x8& pB = J ? paJ1B : paJ0B;
        #pragma unroll
        for (int tc = 0; tc < 4; ++tc) {
            const f16x8 vf = *(const f16x8*)(&Vb[cv][((J * 4 + lg) * 64 + tc * 16 + lm) * 8]);
            accA[tc] = __builtin_amdgcn_mfma_f32_16x16x32_f16(pA, vf, accA[tc], 0, 0, 0);
            accB[tc] = __builtin_amdgcn_mfma_f32_16x16x32_f16(pB, vf, accB[tc], 0, 0, 0);
        }
        accdA = __builtin_amdgcn_mfma_f32_16x16x32_f16(pA, ones, accdA, 0, 0, 0);
        accdB = __builtin_amdgcn_mfma_f32_16x16x32_f16(pB, ones, accdB, 0, 0, 0);
    }
    __builtin_amdgcn_s_setprio(0);

    // ---- store partials ----
    const size_t obA = ((size_t)split * B_ + b) * N_ + qbase;
    if (lm == 0) {
        #pragma unroll
        for (int r = 0; r < 4; ++r) {
            dpart[obA + lg * 4 + r] = accdA[r];
            dpart[obA + 16 + lg * 4 + r] = accdB[r];
        }
    }
    #pragma unroll
    for (int tc = 0; tc < 4; ++tc) {
        #pragma unroll
        for (int r = 0; r < 4; ++r) {
            opart[(obA + lg * 4 + r) * C_ + tc * 16 + lm] = (_Float16)accA[tc][r];
            opart[(obA + 16 + lg * 4 + r) * C_ + tc * 16 + lm] = (_Float16)accB[tc][r];
        }
    }

    // ---- fused combine: last split-partner for (b,qblk) writes out ----
    __syncthreads();            // all threads' partial stores issued
    __threadfence();            // release: make them device-visible
    __syncthreads();
    if (t == 0) {
        const int old = atomicAdd(&cnt[b * 32 + qblk], 1);
        sdone = (old == SPLIT - 1) ? 1 : 0;
    }
    __syncthreads();
    if (sdone) {
        __threadfence();        // acquire partners' writes
        const int nb0 = qblk * QB;
        #pragma unroll
        for (int u = 0; u < 4; ++u) {
            const int unit = u * 256 + t;          // 1024 units: (row 0..127) x (c8 0..7)
            const int row = unit >> 3;
            const int c0 = (unit & 7) * 8;
            const size_t bn = bN + nb0 + row;
            float den = 0.f;
            #pragma unroll
            for (int s = 0; s < SPLIT; ++s) den += dpart[(size_t)s * B_ * N_ + bn];
            const float rden = 1.0f / den;
            float o[8] = {0.f, 0.f, 0.f, 0.f, 0.f, 0.f, 0.f, 0.f};
            #pragma unroll
            for (int s = 0; s < SPLIT; ++s) {
                const f16x8 h = *(const f16x8*)(opart + (((size_t)s * B_ * N_ + bn) * C_ + c0));
                #pragma unroll
                for (int e = 0; e < 8; ++e) o[e] += (float)h[e];
            }
            const size_t base = bn * C_ + c0;
            const f32x4 x0 = *(const f32x4*)(x + base);
            const f32x4 x1 = *(const f32x4*)(x + base + 4);
            f32x4 r0, r1;
            #pragma unroll
            for (int e = 0; e < 4; ++e) {
                r0[e] = x0[e] + o[e] * rden;
                r1[e] = x1[e] + o[e + 4] * rden;
            }
            *(f32x4*)(out + base) = r0;
            *(f32x4*)(out + base + 4) = r1;
        }
    }
}

extern "C" void kernel_launch(void* const* d_in, const int* in_sizes, int n_in,
                              void* d_out, int out_size, void* d_ws, size_t ws_size,
                              hipStream_t stream) {
    const float* x   = (const float*)d_in[0];
    const float* Wq  = (const float*)d_in[1];
    const float* bq  = (const float*)d_in[2];
    const float* Wk  = (const float*)d_in[3];
    const float* bk  = (const float*)d_in[4];
    const float* Wv  = (const float*)d_in[5];
    const float* bv  = (const float*)d_in[6];
    const float* sig = (const float*)d_in[7];
    float* out = (float*)d_out;

    char* ws = (char*)d_ws;
    _Float16* qh   = (_Float16*)(ws);                         // 2 MB   [B][N][32]
    _Float16* khf  = (_Float16*)(ws + (2u << 20));            // 2 MB   [B][N/64][4][64][8]
    _Float16* vhf  = (_Float16*)(ws + (4u << 20));            // 4 MB   [B][N/64][8][64][8]
    float*   nqs   = (float*)(ws + (8u << 20));               // 128 KB [B][N]
    float*   nkf   = (float*)(ws + (8u << 20) + (128u << 10));// 128 KB [B][N/32][32]
    _Float16* opart = (_Float16*)(ws + (8u << 20) + (256u << 10)); // 16 MB [SPLIT][B][N][64]
    float*   dpart = (float*)(ws + (24u << 20) + (256u << 10));    // 512 KB [SPLIT][B][N]
    int*     cnt   = (int*)(ws + (24u << 20) + (768u << 10));      // 1 KB  [B*32]

    proj_kernel<<<512, 256, 0, stream>>>(x, Wq, bq, Wk, bk, Wv, bv, sig,
                                         qh, khf, vhf, nqs, nkf, cnt);
    attn_kernel<<<1024, 256, 0, stream>>>(x, qh, khf, vhf, nqs, nkf,
                                          opart, dpart, cnt, out);
}

// Round 17
// 55.872 us; speedup vs baseline: 3.4319x; 3.4319x over previous
//
#include <hip/hip_runtime.h>
#include <hip/hip_bf16.h>

typedef __attribute__((ext_vector_type(2))) _Float16 f16x2;
typedef __attribute__((ext_vector_type(4))) _Float16 f16x4;
typedef __attribute__((ext_vector_type(8))) _Float16 f16x8;
typedef __attribute__((ext_vector_type(4))) float f32x4;

#define B_ 8
#define N_ 4096
#define C_ 64
#define CQ_ 32
#define SPLIT 4
#define KEYS (N_ / SPLIT)
#define NT (KEYS / 64)   // 16
#define QB 128           // queries per block (4 waves x 32)

#define L2E_ 1.4426950408889634f
#define LOG2L_ 0.5287663729448977f

// minimax cubic for 2^y on [0, 1.443]
#define P0_ 0.9992f
#define P1_ 0.70591f
#define P2_ 0.20093f
#define P3_ 0.094395f

__device__ __forceinline__ void async16(void* lds, const void* gsrc) {
    __builtin_amdgcn_global_load_lds(
        (const __attribute__((address_space(1))) unsigned int*)gsrc,
        (__attribute__((address_space(3))) unsigned int*)lds, 16, 0, 0);
}

// packed f16 evaluation of 2^z on z in [0, 1.443]
__device__ __forceinline__ f16x2 wpoly(float z0, float z1) {
    f16x2 h = __builtin_bit_cast(f16x2, __builtin_amdgcn_cvt_pkrtz(z0, z1));
    const _Float16 c3 = (_Float16)P3_, c2 = (_Float16)P2_;
    const _Float16 c1 = (_Float16)P1_, c0 = (_Float16)P0_;
    return ((h * c3 + c2) * h + c1) * h + c0;
}

// ---------------- projection kernel v8: MFMA-based 1x1 conv ----------------
// grid 512 (b, 64-pixel tile), 256 threads (4 waves). wave = role (q/k/v-lo/v-hi).
__global__ __launch_bounds__(256) void proj_kernel(
    const float* __restrict__ x,
    const float* __restrict__ Wq, const float* __restrict__ bq,
    const float* __restrict__ Wk, const float* __restrict__ bk,
    const float* __restrict__ Wv, const float* __restrict__ bv,
    const float* __restrict__ sigp,
    _Float16* __restrict__ qh, _Float16* __restrict__ khf,
    _Float16* __restrict__ vhf,
    float* __restrict__ nqs, float* __restrict__ nkf)
{
    __shared__ __align__(16) _Float16 xs16[64][72];   // [pix][ch] f16
    __shared__ __align__(16) _Float16 vtmp[64][76];   // [ch][pix] f16

    const int t = threadIdx.x;
    const int wid = __builtin_amdgcn_readfirstlane(t >> 6);
    const int l = t & 63;
    const int lg = l >> 4;
    const int lm = l & 15;
    const int b = blockIdx.x >> 6;
    const int tile = blockIdx.x & 63;
    const int n0 = tile * 64;
    const size_t bN = (size_t)b * N_;

    // ---- stage x tile transposed to f16 ----
    {
        const int c = t >> 2, pq = t & 3;
        const float* xp = x + ((size_t)b * C_ + c) * N_ + n0 + pq * 16;
        f32x4 a0 = *(const f32x4*)(xp);
        f32x4 a1 = *(const f32x4*)(xp + 4);
        f32x4 a2 = *(const f32x4*)(xp + 8);
        f32x4 a3 = *(const f32x4*)(xp + 12);
        #pragma unroll
        for (int i = 0; i < 4; ++i) {
            xs16[pq * 16 + i][c]      = (_Float16)a0[i];
            xs16[pq * 16 + 4 + i][c]  = (_Float16)a1[i];
            xs16[pq * 16 + 8 + i][c]  = (_Float16)a2[i];
            xs16[pq * 16 + 12 + i][c] = (_Float16)a3[i];
        }
    }
    __syncthreads();

    const float* Wr;
    const float* br;
    if (wid == 0)      { Wr = Wq;            br = bq; }
    else if (wid == 1) { Wr = Wk;            br = bk; }
    else if (wid == 2) { Wr = Wv;            br = bv; }
    else               { Wr = Wv + 32 * 64;  br = bv + 32; }

    f16x8 af[2][2];
    #pragma unroll
    for (int og = 0; og < 2; ++og) {
        #pragma unroll
        for (int ks = 0; ks < 2; ++ks) {
            const float* wp = Wr + (og * 16 + lm) * 64 + ks * 32 + lg * 8;
            const f32x4 w0 = *(const f32x4*)(wp);
            const f32x4 w1 = *(const f32x4*)(wp + 4);
            f16x8 h;
            #pragma unroll
            for (int e = 0; e < 4; ++e) { h[e] = (_Float16)w0[e]; h[4 + e] = (_Float16)w1[e]; }
            af[og][ks] = h;
        }
    }
    f32x4 bias[2];
    #pragma unroll
    for (int og = 0; og < 2; ++og)
        bias[og] = *(const f32x4*)(br + og * 16 + lg * 4);

    f32x4 d[2][4];
    #pragma unroll
    for (int pg = 0; pg < 4; ++pg) {
        const f16x8 bf0 = *(const f16x8*)(&xs16[pg * 16 + lm][lg * 8]);
        const f16x8 bf1 = *(const f16x8*)(&xs16[pg * 16 + lm][32 + lg * 8]);
        #pragma unroll
        for (int og = 0; og < 2; ++og) {
            f32x4 acc = __builtin_amdgcn_mfma_f32_16x16x32_f16(af[og][0], bf0, bias[og], 0, 0, 0);
            d[og][pg] = __builtin_amdgcn_mfma_f32_16x16x32_f16(af[og][1], bf1, acc, 0, 0, 0);
        }
    }

    const float sv = sigp[0];
    const float cdL = 0.7213475204444817f / (sv * sv);  // (log2e/2)/sigma^2
    const float c1 = 2.0f * cdL;

    if (wid < 2) {
        float s[4];
        #pragma unroll
        for (int pg = 0; pg < 4; ++pg) {
            float acc = 0.f;
            #pragma unroll
            for (int og = 0; og < 2; ++og)
                #pragma unroll
                for (int r = 0; r < 4; ++r)
                    acc = fmaf(d[og][pg][r], d[og][pg][r], acc);
            acc += __shfl_xor(acc, 16);
            acc += __shfl_xor(acc, 32);
            s[pg] = acc;
        }
        if (wid == 0) {      // ---- q: scale by c1, row-major store ----
            #pragma unroll
            for (int og = 0; og < 2; ++og) {
                #pragma unroll
                for (int pg = 0; pg < 4; ++pg) {
                    f16x4 h;
                    #pragma unroll
                    for (int r = 0; r < 4; ++r) h[r] = (_Float16)(d[og][pg][r] * c1);
                    *(f16x4*)(qh + (bN + n0 + pg * 16 + lm) * CQ_ + og * 16 + lg * 4) = h;
                }
            }
            if (l < 16) {
                #pragma unroll
                for (int pg = 0; pg < 4; ++pg)
                    nqs[bN + n0 + pg * 16 + l] = LOG2L_ - s[pg] * cdL;
            }
        } else {             // ---- k: granule-major tile store + nkf (kappa order) ----
            const size_t tbase = ((size_t)b * (N_ / 64) + tile) * 4;
            #pragma unroll
            for (int og = 0; og < 2; ++og) {
                const int g = og * 2 + (lg >> 1);
                const int e0 = (lg & 1) * 4;
                #pragma unroll
                for (int pg = 0; pg < 4; ++pg) {
                    f16x4 h;
                    #pragma unroll
                    for (int r = 0; r < 4; ++r) h[r] = (_Float16)d[og][pg][r];
                    *(f16x4*)(khf + (tbase + g) * 512 + (pg * 16 + lm) * 8 + e0) = h;
                }
            }
            if (l < 16) {
                #pragma unroll
                for (int pg = 0; pg < 4; ++pg) {
                    const int kkg = n0 + pg * 16 + l;
                    const int kk = kkg & 31;
                    const int kap = (((kk & 15) >> 2) << 3) + (kk & 3) + (((kk >> 4) & 1) << 2);
                    nkf[((size_t)b * (N_ / 32) + (kkg >> 5)) * 32 + kap] = -s[pg] * cdL;
                }
            }
        }
    } else {
        const int co = (wid - 2) * 32;
        #pragma unroll
        for (int og = 0; og < 2; ++og)
            #pragma unroll
            for (int pg = 0; pg < 4; ++pg)
                #pragma unroll
                for (int r = 0; r < 4; ++r)
                    vtmp[co + og * 16 + lg * 4 + r][pg * 16 + lm] = (_Float16)d[og][pg][r];
    }
    __syncthreads();

    #pragma unroll
    for (int p = 0; p < 2; ++p) {
        const int jg = (t >> 6) + p * 4;
        const int ch = t & 63;
        const int p0 = (jg >> 2) * 32 + (jg & 3) * 4;
        const f16x4 a0 = *(const f16x4*)(&vtmp[ch][p0]);
        const f16x4 a1 = *(const f16x4*)(&vtmp[ch][p0 + 16]);
        f16x8 hv;
        #pragma unroll
        for (int e = 0; e < 4; ++e) { hv[e] = a0[e]; hv[4 + e] = a1[e]; }
        *(f16x8*)(vhf + ((size_t)b * (N_ / 64) + tile) * 4096 + (size_t)(jg * 64 + ch) * 8) = hv;
    }
}

// ---------------- fused RBF-attention (r11 champion, verbatim) ----------------
// grid 1024, 256 threads (4 waves), 4 blocks/CU, 32 q/wave. Rolled loop.
// Iter tt: QK(tt) -> [PV(tt-1) hides S latency] -> poly(tt). Tri-buffer glds.
__global__ __launch_bounds__(256, 4) void attn_kernel(
    const _Float16* __restrict__ qh,
    const _Float16* __restrict__ khf,
    const _Float16* __restrict__ vhf,
    const float* __restrict__ nqs,
    const float* __restrict__ nkf,
    _Float16* __restrict__ opart,
    float* __restrict__ dpart)
{
    __shared__ __align__(16) _Float16 Kb[3][2048];   // per tile: [g:4][key:64][8]
    __shared__ __align__(16) _Float16 Vb[3][4096];   // per tile: [j:2][g:4][ch:64][8]
    __shared__ __align__(16) float sNkAll[1024];     // nk for all KEYS (kappa order)

    const int t = threadIdx.x;
    const int wid = t >> 6;
    const int l = t & 63;
    const int lg = l >> 4;
    const int lm = l & 15;

    // bijective XCD swizzle (grid 1024): 128 consecutive wgid per XCD
    const int orig = blockIdx.x;
    const int wgid = (orig & 7) * 128 + (orig >> 3);
    const int qblk = wgid & 31;
    const int fam = wgid >> 5;                 // b*SPLIT + split
    const int split = fam & (SPLIT - 1);
    const int b = fam >> 2;
    const int qbase = qblk * QB + wid * 32;
    const int k0 = split * KEYS;
    const size_t bN = (size_t)b * N_;

    const f16x8 qfA = *(const f16x8*)(qh + (bN + qbase + lm) * CQ_ + 8 * lg);
    const f16x8 qfB = *(const f16x8*)(qh + (bN + qbase + 16 + lm) * CQ_ + 8 * lg);
    const float nqA = nqs[bN + qbase + lm];
    const float nqB = nqs[bN + qbase + 16 + lm];

    const _Float16* kg = khf + ((size_t)b * (N_ / 64) + (k0 >> 6)) * 2048 + wid * 512 + l * 8;
    const _Float16* vg = vhf + ((size_t)b * (N_ / 64) + (k0 >> 6)) * 4096 + wid * 1024 + l * 8;
    const float* nkp = nkf + bN + k0 + wid * 256 + l * 4;

    f32x4 accA[4], accB[4], accdA, accdB;
    #pragma unroll
    for (int i = 0; i < 4; ++i) {
        accA[i] = (f32x4){0.f, 0.f, 0.f, 0.f};
        accB[i] = (f32x4){0.f, 0.f, 0.f, 0.f};
    }
    accdA = (f32x4){0.f, 0.f, 0.f, 0.f};
    accdB = (f32x4){0.f, 0.f, 0.f, 0.f};
    f16x8 ones;
    #pragma unroll
    for (int e = 0; e < 8; ++e) ones[e] = (_Float16)1.0f;

    // pa fragments: single buffer per J-half (old value consumed by PV before overwrite)
    f16x8 paJ0A, paJ0B, paJ1A, paJ1B;

    auto ISSUE = [&](int tile, int bf) {
        async16(&Kb[bf][wid * 512],        kg + (size_t)tile * 2048);
        async16(&Vb[bf][wid * 1024],       vg + (size_t)tile * 4096);
        async16(&Vb[bf][wid * 1024 + 512], vg + (size_t)tile * 4096 + 512);
    };

    // One J-half: QK(tt) MFMAs -> PV(tt-1, old pa) -> poly(tt) -> new pa
    auto HALF = [&](int J, int tt, int ck, int cv, bool doPV, f16x8& pA, f16x8& pB) {
        const f16x8 kf0 = *(const f16x8*)(&Kb[ck][(lg * 64 + J * 32 + lm) * 8]);
        const f16x8 kf1 = *(const f16x8*)(&Kb[ck][(lg * 64 + J * 32 + 16 + lm) * 8]);
        const f32x4 NK0 = *(const f32x4*)(&sNkAll[tt * 64 + J * 32 + lg * 8]);
        const f32x4 NK1 = *(const f32x4*)(&sNkAll[tt * 64 + J * 32 + lg * 8 + 4]);
        f32x4 CA0, CA1, CB0, CB1;
        #pragma unroll
        for (int r = 0; r < 4; ++r) {
            CA0[r] = NK0[r] + nqA; CA1[r] = NK1[r] + nqA;
            CB0[r] = NK0[r] + nqB; CB1[r] = NK1[r] + nqB;
        }
        __builtin_amdgcn_s_setprio(1);
        const f32x4 SA0 = __builtin_amdgcn_mfma_f32_16x16x32_f16(kf0, qfA, CA0, 0, 0, 0);
        const f32x4 SA1 = __builtin_amdgcn_mfma_f32_16x16x32_f16(kf1, qfA, CA1, 0, 0, 0);
        const f32x4 SB0 = __builtin_amdgcn_mfma_f32_16x16x32_f16(kf0, qfB, CB0, 0, 0, 0);
        const f32x4 SB1 = __builtin_amdgcn_mfma_f32_16x16x32_f16(kf1, qfB, CB1, 0, 0, 0);
        __builtin_amdgcn_s_setprio(0);
        if (doPV) {   // PV for tile tt-1 using OLD pA/pB — hides S latency
            __builtin_amdgcn_s_setprio(1);
            #pragma unroll
            for (int tc = 0; tc < 4; ++tc) {
                const f16x8 vf = *(const f16x8*)(&Vb[cv][((J * 4 + lg) * 64 + tc * 16 + lm) * 8]);
                accA[tc] = __builtin_amdgcn_mfma_f32_16x16x32_f16(pA, vf, accA[tc], 0, 0, 0);
                accB[tc] = __builtin_amdgcn_mfma_f32_16x16x32_f16(pB, vf, accB[tc], 0, 0, 0);
            }
            accdA = __builtin_amdgcn_mfma_f32_16x16x32_f16(pA, ones, accdA, 0, 0, 0);
            accdB = __builtin_amdgcn_mfma_f32_16x16x32_f16(pB, ones, accdB, 0, 0, 0);
            __builtin_amdgcn_s_setprio(0);
        }
        // z = 2^(S+nk+nq) in [0,1.44]; w = poly_f16(z)
        f16x2 w;
        w = wpoly(__builtin_amdgcn_exp2f(SA0[0]), __builtin_amdgcn_exp2f(SA0[1])); pA[0] = w[0]; pA[1] = w[1];
        w = wpoly(__builtin_amdgcn_exp2f(SA0[2]), __builtin_amdgcn_exp2f(SA0[3])); pA[2] = w[0]; pA[3] = w[1];
        w = wpoly(__builtin_amdgcn_exp2f(SA1[0]), __builtin_amdgcn_exp2f(SA1[1])); pA[4] = w[0]; pA[5] = w[1];
        w = wpoly(__builtin_amdgcn_exp2f(SA1[2]), __builtin_amdgcn_exp2f(SA1[3])); pA[6] = w[0]; pA[7] = w[1];
        w = wpoly(__builtin_amdgcn_exp2f(SB0[0]), __builtin_amdgcn_exp2f(SB0[1])); pB[0] = w[0]; pB[1] = w[1];
        w = wpoly(__builtin_amdgcn_exp2f(SB0[2]), __builtin_amdgcn_exp2f(SB0[3])); pB[2] = w[0]; pB[3] = w[1];
        w = wpoly(__builtin_amdgcn_exp2f(SB1[0]), __builtin_amdgcn_exp2f(SB1[1])); pB[4] = w[0]; pB[5] = w[1];
        w = wpoly(__builtin_amdgcn_exp2f(SB1[2]), __builtin_amdgcn_exp2f(SB1[3])); pB[6] = w[0]; pB[7] = w[1];
    };

    // ---- prologue: nk (all keys) + tile 0; then QK+poly(0) with no PV ----
    async16(&sNkAll[wid * 256], nkp);
    ISSUE(0, 0);
    asm volatile("s_waitcnt vmcnt(0)" ::: "memory");
    asm volatile("s_barrier" ::: "memory");
    ISSUE(1, 1);
    HALF(0, 0, 0, 0, false, paJ0A, paJ0B);
    HALF(1, 0, 0, 0, false, paJ1A, paJ1B);

    int cv = 0, ck = 1, ib = 2;
    #pragma unroll 1
    for (int tt = 1; tt < NT; ++tt) {
        asm volatile("s_waitcnt vmcnt(0)" ::: "memory");   // own ISSUE(tt) landed
        asm volatile("s_barrier" ::: "memory");            // all waves' ISSUE(tt) landed
        if (tt + 1 < NT) ISSUE(tt + 1, ib);                // safe: buf ib last read 2 iters ago
        HALF(0, tt, ck, cv, true, paJ0A, paJ0B);
        HALF(1, tt, ck, cv, true, paJ1A, paJ1B);
        const int tmp = cv; cv = ck; ck = ib; ib = tmp;
    }

    // ---- epilogue: PV for tile NT-1 (buffer = cv after final rotation) ----
    __builtin_amdgcn_s_setprio(1);
    #pragma unroll
    for (int J = 0; J < 2; ++J) {
        const f16x8& pA = J ? paJ1A : paJ0A;
        const f16x8& pB = J ? paJ1B : paJ0B;
        #pragma unroll
        for (int tc = 0; tc < 4; ++tc) {
            const f16x8 vf = *(const f16x8*)(&Vb[cv][((J * 4 + lg) * 64 + tc * 16 + lm) * 8]);
            accA[tc] = __builtin_amdgcn_mfma_f32_16x16x32_f16(pA, vf, accA[tc], 0, 0, 0);
            accB[tc] = __builtin_amdgcn_mfma_f32_16x16x32_f16(pB, vf, accB[tc], 0, 0, 0);
        }
        accdA = __builtin_amdgcn_mfma_f32_16x16x32_f16(pA, ones, accdA, 0, 0, 0);
        accdB = __builtin_amdgcn_mfma_f32_16x16x32_f16(pB, ones, accdB, 0, 0, 0);
    }
    __builtin_amdgcn_s_setprio(0);

    // ---- store partials: D[query at lg*4+r][channel at lm] ----
    const size_t obA = ((size_t)split * B_ + b) * N_ + qbase;
    if (lm == 0) {
        #pragma unroll
        for (int r = 0; r < 4; ++r) {
            dpart[obA + lg * 4 + r] = accdA[r];
            dpart[obA + 16 + lg * 4 + r] = accdB[r];
        }
    }
    #pragma unroll
    for (int tc = 0; tc < 4; ++tc) {
        #pragma unroll
        for (int r = 0; r < 4; ++r) {
            opart[(obA + lg * 4 + r) * C_ + tc * 16 + lm] = (_Float16)accA[tc][r];
            opart[(obA + 16 + lg * 4 + r) * C_ + tc * 16 + lm] = (_Float16)accB[tc][r];
        }
    }
}

// ---------------- combine kernel: sum partials, divide, add x ----------------
__global__ __launch_bounds__(256) void combine_kernel(
    const float* __restrict__ x,
    const _Float16* __restrict__ opart,
    const float* __restrict__ dpart,
    float* __restrict__ out)
{
    const int gid = blockIdx.x * 256 + threadIdx.x;
    const int c0 = (gid & 7) * 8;
    const int bn = gid >> 3;

    float den = 0.f;
    #pragma unroll
    for (int s = 0; s < SPLIT; ++s) den += dpart[(size_t)s * B_ * N_ + bn];
    const float rden = 1.0f / den;

    float o[8] = {0.f, 0.f, 0.f, 0.f, 0.f, 0.f, 0.f, 0.f};
    #pragma unroll
    for (int s = 0; s < SPLIT; ++s) {
        const f16x8 h = *(const f16x8*)(opart + (((size_t)s * B_ * N_ + bn) * C_ + c0));
        #pragma unroll
        for (int e = 0; e < 8; ++e) o[e] += (float)h[e];
    }

    const size_t base = (size_t)bn * C_ + c0;
    const f32x4 x0 = *(const f32x4*)(x + base);
    const f32x4 x1 = *(const f32x4*)(x + base + 4);
    f32x4 r0, r1;
    #pragma unroll
    for (int e = 0; e < 4; ++e) {
        r0[e] = x0[e] + o[e] * rden;
        r1[e] = x1[e] + o[e + 4] * rden;
    }
    *(f32x4*)(out + base) = r0;
    *(f32x4*)(out + base + 4) = r1;
}

extern "C" void kernel_launch(void* const* d_in, const int* in_sizes, int n_in,
                              void* d_out, int out_size, void* d_ws, size_t ws_size,
                              hipStream_t stream) {
    const float* x   = (const float*)d_in[0];
    const float* Wq  = (const float*)d_in[1];
    const float* bq  = (const float*)d_in[2];
    const float* Wk  = (const float*)d_in[3];
    const float* bk  = (const float*)d_in[4];
    const float* Wv  = (const float*)d_in[5];
    const float* bv  = (const float*)d_in[6];
    const float* sig = (const float*)d_in[7];
    float* out = (float*)d_out;

    char* ws = (char*)d_ws;
    _Float16* qh   = (_Float16*)(ws);                         // 2 MB   [B][N][32]
    _Float16* khf  = (_Float16*)(ws + (2u << 20));            // 2 MB   [B][N/64][4][64][8]
    _Float16* vhf  = (_Float16*)(ws + (4u << 20));            // 4 MB   [B][N/64][8][64][8]
    float*   nqs   = (float*)(ws + (8u << 20));               // 128 KB [B][N]
    float*   nkf   = (float*)(ws + (8u << 20) + (128u << 10));// 128 KB [B][N/32][32]
    _Float16* opart = (_Float16*)(ws + (8u << 20) + (256u << 10)); // 16 MB [SPLIT][B][N][64]
    float*   dpart = (float*)(ws + (24u << 20) + (256u << 10));    // 512 KB [SPLIT][B][N]

    proj_kernel<<<512, 256, 0, stream>>>(x, Wq, bq, Wk, bk, Wv, bv, sig,
                                         qh, khf, vhf, nqs, nkf);
    attn_kernel<<<1024, 256, 0, stream>>>(qh, khf, vhf, nqs, nkf, opart, dpart);
    combine_kernel<<<(B_ * N_ * 8) / 256, 256, 0, stream>>>(x, opart, dpart, out);
}